// Round 8
// baseline (65108.209 us; speedup 1.0000x reference)
//
#include <hip/hip_runtime.h>
#include <math.h>

// h_t = tanh(A h_{t-1} + B x_t + c), A = 0.9 I + 0.1 A_raw
// T=16384, X=512, H=1024, fp32. Output: all h_t, [T, H].
//
// Phase 1: Bx = x @ B^T + c written in-place into d_out.
// Phase 2: XCD-LOCAL tagged-ring scan (round-8 hypothesis test):
//   - Round-2 postmortem: sc0-ONLY polls spun on STALE L2 lines because the
//     producer's sc0|sc1 store bypasses the local L2 without invalidating
//     it. That refuted {sc1-store -> sc0-load}, NOT {sc0-store -> sc0-load}.
//     This round tests the untested cell: producer stores packets TWICE to
//     the SAME address -- once sc0 (updates the winner XCD's shared L2,
//     RT ~200-250cy) and once sc0 sc1 (LLC, the validated liveness path).
//     Consumers poll sc0 up to 12 spins; if any lane misses, the wave
//     STICKILY escalates to the validated sc0 sc1 poll for all remaining
//     steps. Tags make stale data self-identifying in every cache world;
//     liveness never depends on the L2 hypothesis.
//   - Election (validated round 2): 256 candidate blocks; per-XCD claim
//     counters (device atomics); first XCD to 32 claimants is CAS-elected;
//     its 32 blocks proceed (1/CU on the winning XCD), rest exit.
//     Pigeonhole: all 256 candidates resident (512 thr, 8.2KB LDS, ~70
//     VGPR -> >=1/CU) -> all claim -> max-XCD >= ceil(256/8) = 32.
//   - 32 blocks x 512 threads; wave w of block b owns rows 32b+4w..+3
//     (aw[4][16]; float4 Bx prefetch + out store; 2 packet-pair stores).
//   - Ring depth 3 (validated round 2; reaching step t implies all blocks
//     passed step t-1's poll, hence finished reading slot t%3 at t-2).
//     Workspace: 3*8KB slots + 36B ctrl = 24612B.
//   - Compute tail = round-6 validated DPP reduction + fast_tanh. Per-row
//     FMA order, DPP tree, tanh identical -> absmax must be exactly
//     0.00390625 (the schedule/transport-only validation signal).

#define T_STEPS 16384
#define XD 512
#define HD 1024
#define NWIN 32          // winner blocks (one XCD)
#define NCAND 256        // candidate blocks launched

typedef unsigned int uint32x4 __attribute__((ext_vector_type(4)));

// DPP-accumulate: v += dpp_mov(v, ctrl); bound_ctrl=true -> invalid lanes
// contribute 0.0f. (Validated round 6.)
#define DPP_ADD(v, ctrl, rm)                                          \
    v += __int_as_float(__builtin_amdgcn_update_dpp(                  \
        0, __float_as_int(v), ctrl, rm, 0xf, true))

__device__ __forceinline__ float fast_tanh(float x)
{
    const float e = __expf(2.0f * x);
    return 1.0f - 2.0f / (e + 1.0f);
}

// ---------------------------------------------------------------------------
// Phase 1: GEMM  out[t][i] = sum_k x[t][k] * B[i][k] + c[i]   (unchanged)
// ---------------------------------------------------------------------------
__global__ __launch_bounds__(256) void gemm_bx_kernel(
    const float* __restrict__ x, const float* __restrict__ B,
    const float* __restrict__ c, float* __restrict__ out)
{
    __shared__ __align__(16) float xs[32][68];  // [k][t]
    __shared__ __align__(16) float bs[32][68];  // [k][i]

    const int tid = threadIdx.x;
    const int t0 = blockIdx.x * 64;
    const int i0 = blockIdx.y * 64;
    const int tx = tid & 15;
    const int ty = tid >> 4;
    const int lr = tid >> 3;
    const int lc = (tid & 7) << 2;

    float acc[4][4] = {{0.f}};

    for (int k0 = 0; k0 < XD; k0 += 32) {
        const float4 xa = *(const float4*)&x[(size_t)(t0 + lr) * XD + k0 + lc];
        const float4 xb = *(const float4*)&x[(size_t)(t0 + lr + 32) * XD + k0 + lc];
        const float4 ba = *(const float4*)&B[(size_t)(i0 + lr) * XD + k0 + lc];
        const float4 bb = *(const float4*)&B[(size_t)(i0 + lr + 32) * XD + k0 + lc];
        __syncthreads();
        xs[lc + 0][lr] = xa.x; xs[lc + 1][lr] = xa.y; xs[lc + 2][lr] = xa.z; xs[lc + 3][lr] = xa.w;
        xs[lc + 0][lr + 32] = xb.x; xs[lc + 1][lr + 32] = xb.y; xs[lc + 2][lr + 32] = xb.z; xs[lc + 3][lr + 32] = xb.w;
        bs[lc + 0][lr] = ba.x; bs[lc + 1][lr] = ba.y; bs[lc + 2][lr] = ba.z; bs[lc + 3][lr] = ba.w;
        bs[lc + 0][lr + 32] = bb.x; bs[lc + 1][lr + 32] = bb.y; bs[lc + 2][lr + 32] = bb.z; bs[lc + 3][lr + 32] = bb.w;
        __syncthreads();
        #pragma unroll
        for (int k = 0; k < 32; ++k) {
            const float4 av = *(const float4*)&xs[k][ty << 2];
            const float4 bv = *(const float4*)&bs[k][tx << 2];
            const float am[4] = {av.x, av.y, av.z, av.w};
            const float bn[4] = {bv.x, bv.y, bv.z, bv.w};
            #pragma unroll
            for (int m = 0; m < 4; ++m)
                #pragma unroll
                for (int n = 0; n < 4; ++n)
                    acc[m][n] = fmaf(am[m], bn[n], acc[m][n]);
        }
    }

    #pragma unroll
    for (int m = 0; m < 4; ++m) {
        const int trow = t0 + (ty << 2) + m;
        #pragma unroll
        for (int n = 0; n < 4; ++n) {
            const int icol = i0 + (tx << 2) + n;
            out[(size_t)trow * HD + icol] = acc[m][n] + c[icol];
        }
    }
}

// ---------------------------------------------------------------------------
// Ring + control init (d_ws is poisoned 0xAA before every launch).
// slots: ull[3][1024]; ring[2] = h0 tag 0; rings 0,1 = impossible tag.
// ctrl:  [0..7] per-XCD claim counters = 0, [8] winner = 0xFFFFFFFF.
// Kernel completion flushes caches -> scan kernel sees all of this.
// ---------------------------------------------------------------------------
__global__ void init_slots_kernel(unsigned long long* slots, unsigned* ctrl,
                                  const float* h0)
{
    const int i = threadIdx.x;  // 1024 threads
    union { float f; unsigned u; } v; v.f = h0[i];
    slots[2 * HD + i] = (unsigned long long)v.u;          // tag 0 | h0 bits
    slots[0 * HD + i] = 0xFFFFFFFF00000000ull;
    slots[1 * HD + i] = 0xFFFFFFFF00000000ull;
    if (i < 9) ctrl[i] = (i == 8) ? 0xFFFFFFFFu : 0u;
}

// ---------------------------------------------------------------------------
// Phase 2: XCD-local scan. 256 candidates; 32 winners (one XCD); winner
// block b's wave w owns rows 32b + 4w .. +3.
// ---------------------------------------------------------------------------
__global__ __launch_bounds__(512) void rnn_scan_kernel(
    const float* __restrict__ A_raw, float* out,
    unsigned long long* slots, unsigned* ctrl)
{
    // ---- XCD election (validated round 2) ---------------------------------
    __shared__ int s_bid;
    if (threadIdx.x == 0) {
        unsigned xcd;
        asm volatile("s_getreg_b32 %0, hwreg(HW_REG_XCC_ID)" : "=s"(xcd));
        xcd &= 7u;
        int my = -1;
        const unsigned slot = atomicAdd(&ctrl[xcd], 1u);
        if (slot < (unsigned)NWIN) {
            if (slot == (unsigned)(NWIN - 1))
                atomicCAS(&ctrl[8], 0xFFFFFFFFu, xcd);
            unsigned w;
            const unsigned* wp = &ctrl[8];
            do {
                asm volatile(
                    "global_load_dword %0, %1, off sc0 sc1\n\t"
                    "s_waitcnt vmcnt(0)"
                    : "=v"(w) : "v"(wp));
            } while (w == 0xFFFFFFFFu);
            if (w == xcd) my = (int)slot;
        }
        s_bid = my;
    }
    __syncthreads();
    const int bid = s_bid;       // 0..31 on the winning XCD, else -1
    if (bid < 0) return;

    // ---- scan -------------------------------------------------------------
    const int tid = threadIdx.x;       // 0..511
    const int wave = tid >> 6;         // 0..7
    const int lane = tid & 63;
    const int r0 = (bid << 5) + (wave << 2);   // rows r0 .. r0+3

    __shared__ float hlds[2][HD];

    // Effective A rows: A_eff[r][k] = 0.1*A_raw[r][k] + 0.9*(k==r)
    float aw[4][16];
    #pragma unroll
    for (int r = 0; r < 4; ++r)
        #pragma unroll
        for (int j = 0; j < 16; ++j) {
            const int k = lane + (j << 6);
            float v = 0.1f * A_raw[(size_t)(r0 + r) * HD + k];
            if (k == r0 + r) v += 0.9f;
            aw[r][j] = v;
        }

    // Prefetch Bx for t=0.
    float4 bxn = *(const float4*)&out[r0];

    int cs = 2;        // ring slot of h_{t-1} (h0 lives in slot 2)
    int ps = 0;        // ring slot of h_t
    bool esc = false;  // sticky per-wave escalation to the LLC poll path

    for (int t = 0; t < T_STEPS; ++t) {
        const float4 bx = bxn;

        // ---- poll my two adjacent slots of h_{t-1}; expect tag t ---------
        const unsigned long long* sp =
            slots + ((size_t)cs << 10) + (tid << 1);
        uint32x4 s;
        if (!esc) {
            // Fast path: same-XCD L2 (sc0 store -> sc0 load). vmcnt(0)
            // inside the asm: writeback synchronous, no register hazards.
            bool got = false;
            for (int spin = 0; spin < 12 && !got; ++spin) {
                asm volatile(
                    "global_load_dwordx4 %0, %1, off sc0\n\t"
                    "s_waitcnt vmcnt(0)"
                    : "=v"(s) : "v"(sp));
                got = (s.y == (unsigned)t && s.w == (unsigned)t);
            }
            if (!__all(got)) esc = true;   // wave-uniform, sticky
        }
        if (esc) {
            // Validated LLC path (liveness guaranteed by the sc0 sc1 store).
            do {
                asm volatile(
                    "global_load_dwordx4 %0, %1, off sc0 sc1\n\t"
                    "s_waitcnt vmcnt(0)"
                    : "=v"(s) : "v"(sp));
            } while (s.y != (unsigned)t || s.w != (unsigned)t);
        }

        union { unsigned u; float f; } c0, c1; c0.u = s.x; c1.u = s.z;
        *(float2*)&hlds[t & 1][tid << 1] = make_float2(c0.f, c1.f);
        __syncthreads();

        // Prefetch next step's Bx while h is consumed.
        const int tn = (t + 1 < T_STEPS) ? (t + 1) : t;
        bxn = *(const float4*)&out[(size_t)tn * HD + r0];

        // All 4 rows' dot products from ONE pass over h in LDS.
        const float* hl = hlds[t & 1];
        float p[4] = {0.f, 0.f, 0.f, 0.f};
        #pragma unroll
        for (int j = 0; j < 16; ++j) {
            const float hvj = hl[lane + (j << 6)];
            #pragma unroll
            for (int r = 0; r < 4; ++r)
                p[r] = fmaf(aw[r][j], hvj, p[r]);
        }

        // Wave-wide sums via DPP (validated round 6); full sums in lane 63.
        #pragma unroll
        for (int r = 0; r < 4; ++r) { DPP_ADD(p[r], 0x111, 0xf); }  // shr:1
        #pragma unroll
        for (int r = 0; r < 4; ++r) { DPP_ADD(p[r], 0x112, 0xf); }  // shr:2
        #pragma unroll
        for (int r = 0; r < 4; ++r) { DPP_ADD(p[r], 0x114, 0xf); }  // shr:4
        #pragma unroll
        for (int r = 0; r < 4; ++r) { DPP_ADD(p[r], 0x118, 0xf); }  // shr:8
        #pragma unroll
        for (int r = 0; r < 4; ++r) { DPP_ADD(p[r], 0x142, 0xa); }  // bcast:15
        #pragma unroll
        for (int r = 0; r < 4; ++r) { DPP_ADD(p[r], 0x143, 0xc); }  // bcast:31

        if (lane == 63) {
            const float h0n = fast_tanh(p[0] + bx.x);
            const float h1n = fast_tanh(p[1] + bx.y);
            const float h2n = fast_tanh(p[2] + bx.z);
            const float h3n = fast_tanh(p[3] + bx.w);
            union { float f; unsigned u; } u0, u1, u2, u3;
            u0.f = h0n; u1.f = h1n; u2.f = h2n; u3.f = h3n;
            uint32x4 pkA, pkB;
            pkA.x = u0.u; pkA.y = (unsigned)(t + 1);
            pkA.z = u1.u; pkA.w = (unsigned)(t + 1);
            pkB.x = u2.u; pkB.y = (unsigned)(t + 1);
            pkB.z = u3.u; pkB.w = (unsigned)(t + 1);
            unsigned long long* dp = slots + ((size_t)ps << 10) + r0;
            // Local L2 fast path first (critical for same-XCD consumers),
            // then the LLC write-through (validated liveness), then out.
            asm volatile("global_store_dwordx4 %0, %1, off sc0"
                         :: "v"(dp), "v"(pkA) : "memory");
            asm volatile("global_store_dwordx4 %0, %1, off sc0"
                         :: "v"(dp + 2), "v"(pkB) : "memory");
            asm volatile("global_store_dwordx4 %0, %1, off sc0 sc1"
                         :: "v"(dp), "v"(pkA) : "memory");
            asm volatile("global_store_dwordx4 %0, %1, off sc0 sc1"
                         :: "v"(dp + 2), "v"(pkB) : "memory");
            *(float4*)&out[(size_t)t * HD + r0] =
                make_float4(h0n, h1n, h2n, h3n);
        }

        // Advance ring: cons_{t+1} = prod_t; prod_{t+1} = prod_t + 1 (mod 3).
        cs = ps;
        ps = (ps + 1 == 3) ? 0 : ps + 1;
        // No grid barrier: tags + 3-deep ring + dataflow (skew <= 1).
        // LDS double buffer covers intra-block wave skew.
    }
}

// ---------------------------------------------------------------------------
extern "C" void kernel_launch(void* const* d_in, const int* in_sizes, int n_in,
                              void* d_out, int out_size, void* d_ws, size_t ws_size,
                              hipStream_t stream)
{
    const float* x     = (const float*)d_in[0];  // [16384, 512]
    const float* h0    = (const float*)d_in[1];  // [1024]
    const float* A_raw = (const float*)d_in[2];  // [1024, 1024]
    const float* B     = (const float*)d_in[3];  // [1024, 512]
    const float* c     = (const float*)d_in[4];  // [1024]
    float* out = (float*)d_out;                  // [16384, 1024]
    unsigned long long* slots = (unsigned long long*)d_ws;  // 3 x 1024 x 8B
    unsigned* ctrl = (unsigned*)(slots + 3 * HD);           // 9 x 4B

    dim3 gemm_grid(T_STEPS / 64, HD / 64);       // 256 x 16
    gemm_bx_kernel<<<gemm_grid, 256, 0, stream>>>(x, B, c, out);
    init_slots_kernel<<<1, HD, 0, stream>>>(slots, ctrl, h0);
    rnn_scan_kernel<<<NCAND, 512, 0, stream>>>(A_raw, out, slots, ctrl);
}

// Round 9
// 42148.557 us; speedup vs baseline: 1.5447x; 1.5447x over previous
//
#include <hip/hip_runtime.h>
#include <math.h>

// h_t = tanh(A h_{t-1} + B x_t + c), A = 0.9 I + 0.1 A_raw
// T=16384, X=512, H=1024, fp32. Output: all h_t, [T, H].
//
// Phase 1: Bx = x @ B^T + c written in-place into d_out.
// Phase 2: tagged-slot pipeline over the LLC (sc0 sc1) -- the ONLY coherent
//   inter-block transport on MI355X (rounds 2/7/8 refuted every L2-local
//   cell: sc1-store->sc0-load, global_load_lds, sc0-store->sc0-load; remote
//   stores neither update nor invalidate another CU's L2 view).
//
// ROUND-9 CHANGE -- registers-only exchange (kill the LDS leg):
//   Round 6's post-detect path was: LDS write -> __syncthreads -> 16 strided
//   ds_reads -> dot (~300-400cy serial after detect). Instead, each lane
//   polls its own dot-slice DIRECTLY from the ring: 8x global_load_dwordx4
//   covering its 16 elements e = 2*lane + 128*j (value+tag pairs), issued
//   in ONE asm block that ends with s_waitcnt vmcnt(0):
//     - synchronous at exit -> no in-flight VMEM ever crosses compiler
//       code (the rounds-3-5 soundness rule; register writebacks can't
//       clobber live state).
//     - all 16 tags arrive with the values; wave-uniform __all retry
//       reloads the whole batch (simple, sound).
//   The dot then runs entirely on registers: no LDS, no __syncthreads, no
//   ds_reads. Barrier removal is safe: skew<=1 was always enforced by the
//   all-to-all tag dataflow (every wave needs every wave's step-(t-1)
//   output before step t), never by the intra-block barrier.
//   Element->lane remapping reorders each row's summation -> absmax moves
//   slightly off 0.00390625 (bounded ~1e-3-ish, threshold 2e-2).
//   Producer side unchanged from validated round 6 (one dwordx4 packet
//   {v0,tag,v1,tag} sc0 sc1 + fp32 float2 out store; DPP reduce; fast_tanh).

#define T_STEPS 16384
#define XD 512
#define HD 1024

typedef unsigned int uint32x4 __attribute__((ext_vector_type(4)));

// DPP-accumulate (validated round 6): v += dpp_mov(v, ctrl); bound_ctrl=true
// -> invalid lanes contribute 0.0f. Full 64-lane sum lands in lane 63.
#define DPP_ADD(v, ctrl, rm)                                          \
    v += __int_as_float(__builtin_amdgcn_update_dpp(                  \
        0, __float_as_int(v), ctrl, rm, 0xf, true))

#define VF(u) __uint_as_float(u)

__device__ __forceinline__ float fast_tanh(float x)
{
    const float e = __expf(2.0f * x);
    return 1.0f - 2.0f / (e + 1.0f);
}

// ---------------------------------------------------------------------------
// Phase 1: GEMM  out[t][i] = sum_k x[t][k] * B[i][k] + c[i]   (unchanged)
// ---------------------------------------------------------------------------
__global__ __launch_bounds__(256) void gemm_bx_kernel(
    const float* __restrict__ x, const float* __restrict__ B,
    const float* __restrict__ c, float* __restrict__ out)
{
    __shared__ __align__(16) float xs[32][68];  // [k][t]
    __shared__ __align__(16) float bs[32][68];  // [k][i]

    const int tid = threadIdx.x;
    const int t0 = blockIdx.x * 64;
    const int i0 = blockIdx.y * 64;
    const int tx = tid & 15;
    const int ty = tid >> 4;
    const int lr = tid >> 3;
    const int lc = (tid & 7) << 2;

    float acc[4][4] = {{0.f}};

    for (int k0 = 0; k0 < XD; k0 += 32) {
        const float4 xa = *(const float4*)&x[(size_t)(t0 + lr) * XD + k0 + lc];
        const float4 xb = *(const float4*)&x[(size_t)(t0 + lr + 32) * XD + k0 + lc];
        const float4 ba = *(const float4*)&B[(size_t)(i0 + lr) * XD + k0 + lc];
        const float4 bb = *(const float4*)&B[(size_t)(i0 + lr + 32) * XD + k0 + lc];
        __syncthreads();
        xs[lc + 0][lr] = xa.x; xs[lc + 1][lr] = xa.y; xs[lc + 2][lr] = xa.z; xs[lc + 3][lr] = xa.w;
        xs[lc + 0][lr + 32] = xb.x; xs[lc + 1][lr + 32] = xb.y; xs[lc + 2][lr + 32] = xb.z; xs[lc + 3][lr + 32] = xb.w;
        bs[lc + 0][lr] = ba.x; bs[lc + 1][lr] = ba.y; bs[lc + 2][lr] = ba.z; bs[lc + 3][lr] = ba.w;
        bs[lc + 0][lr + 32] = bb.x; bs[lc + 1][lr + 32] = bb.y; bs[lc + 2][lr + 32] = bb.z; bs[lc + 3][lr + 32] = bb.w;
        __syncthreads();
        #pragma unroll
        for (int k = 0; k < 32; ++k) {
            const float4 av = *(const float4*)&xs[k][ty << 2];
            const float4 bv = *(const float4*)&bs[k][tx << 2];
            const float am[4] = {av.x, av.y, av.z, av.w};
            const float bn[4] = {bv.x, bv.y, bv.z, bv.w};
            #pragma unroll
            for (int m = 0; m < 4; ++m)
                #pragma unroll
                for (int n = 0; n < 4; ++n)
                    acc[m][n] = fmaf(am[m], bn[n], acc[m][n]);
        }
    }

    #pragma unroll
    for (int m = 0; m < 4; ++m) {
        const int trow = t0 + (ty << 2) + m;
        #pragma unroll
        for (int n = 0; n < 4; ++n) {
            const int icol = i0 + (tx << 2) + n;
            out[(size_t)trow * HD + icol] = acc[m][n] + c[icol];
        }
    }
}

// ---------------------------------------------------------------------------
// Slot-ring init (d_ws is poisoned 0xAA before every launch).
// ring[3] holds h0 with tag 0; rings 0..2 get an impossible tag.
// ---------------------------------------------------------------------------
__global__ void init_slots_kernel(unsigned long long* slots, const float* h0)
{
    const int i = threadIdx.x;  // 1024 threads
    union { float f; unsigned u; } v; v.f = h0[i];
    slots[3 * HD + i] = (unsigned long long)v.u;          // tag 0 | h0 bits
    slots[0 * HD + i] = 0xFFFFFFFF00000000ull;
    slots[1 * HD + i] = 0xFFFFFFFF00000000ull;
    slots[2 * HD + i] = 0xFFFFFFFF00000000ull;
}

// ---------------------------------------------------------------------------
// Phase 2: tagged-slot scan, registers-only exchange.
// 64 blocks x 512 threads; wave w of block b owns rows 16b+2w, +1.
// No LDS, no __syncthreads in the loop.
// ---------------------------------------------------------------------------
__global__ __launch_bounds__(512) void rnn_scan_kernel(
    const float* __restrict__ A_raw, float* out,
    unsigned long long* slots)
{
    const int tid = threadIdx.x;       // 0..511
    const int bid = blockIdx.x;        // 0..63
    const int wave = tid >> 6;         // 0..7
    const int lane = tid & 63;
    const int r0 = (bid << 4) + (wave << 1);   // rows r0, r0+1

    // A coefficients for the NEW element slicing: lane covers elements
    // e = 2*lane + 128*j + b (j=0..7, b=0..1) -> aw{0,1}[2j+b].
    // A_eff[r][k] = 0.1*A_raw[r][k] + 0.9*(k==r)
    float aw0[16], aw1[16];
    #pragma unroll
    for (int j = 0; j < 8; ++j)
        #pragma unroll
        for (int b = 0; b < 2; ++b) {
            const int k = (lane << 1) + (j << 7) + b;
            float v0 = 0.1f * A_raw[(size_t)r0 * HD + k];
            float v1 = 0.1f * A_raw[(size_t)(r0 + 1) * HD + k];
            if (k == r0) v0 += 0.9f;
            if (k == r0 + 1) v1 += 0.9f;
            aw0[(j << 1) + b] = v0; aw1[(j << 1) + b] = v1;
        }

    // Prefetch Bx for t=0.
    float2 bxn = *(const float2*)&out[r0];

    for (int t = 0; t < T_STEPS; ++t) {
        // ---- batch-poll my 16 dot-slice elements of h_{t-1} --------------
        // ring[(t+3)&3]; element e=2*lane+128*j at byte 16*lane + 1024*j.
        // ONE asm block: 8 dwordx4 loads + vmcnt(0) -> synchronous at exit.
        const unsigned long long* b0 =
            slots + ((size_t)((t + 3) & 3) << 10) + (lane << 1);
        const unsigned long long* b1 = b0 + 512;   // +4096 bytes (j=4..7)
        uint32x4 q0, q1, q2, q3, q4, q5, q6, q7;
        const unsigned tt = (unsigned)t;
        for (;;) {
            asm volatile(
                "global_load_dwordx4 %0, %8, off sc0 sc1\n\t"
                "global_load_dwordx4 %1, %8, off offset:1024 sc0 sc1\n\t"
                "global_load_dwordx4 %2, %8, off offset:2048 sc0 sc1\n\t"
                "global_load_dwordx4 %3, %8, off offset:3072 sc0 sc1\n\t"
                "global_load_dwordx4 %4, %9, off sc0 sc1\n\t"
                "global_load_dwordx4 %5, %9, off offset:1024 sc0 sc1\n\t"
                "global_load_dwordx4 %6, %9, off offset:2048 sc0 sc1\n\t"
                "global_load_dwordx4 %7, %9, off offset:3072 sc0 sc1\n\t"
                "s_waitcnt vmcnt(0)"
                : "=&v"(q0), "=&v"(q1), "=&v"(q2), "=&v"(q3),
                  "=&v"(q4), "=&v"(q5), "=&v"(q6), "=&v"(q7)
                : "v"(b0), "v"(b1)
                : "memory");
            const int ok =
                (q0.y == tt) & (q0.w == tt) & (q1.y == tt) & (q1.w == tt) &
                (q2.y == tt) & (q2.w == tt) & (q3.y == tt) & (q3.w == tt) &
                (q4.y == tt) & (q4.w == tt) & (q5.y == tt) & (q5.w == tt) &
                (q6.y == tt) & (q6.w == tt) & (q7.y == tt) & (q7.w == tt);
            if (__all(ok)) break;
        }

        // Capture this step's Bx, then prefetch the next (drained by the
        // next iteration's in-asm vmcnt(0) -> always sound).
        const float2 bx = bxn;
        const int tn = (t + 1 < T_STEPS) ? (t + 1) : t;
        bxn = *(const float2*)&out[(size_t)tn * HD + r0];

        // ---- dot on registers (no LDS): 2 accumulators/row for ILP ------
        float p0a = 0.f, p0b = 0.f, p1a = 0.f, p1b = 0.f;
        p0a = fmaf(aw0[0],  VF(q0.x), p0a); p0b = fmaf(aw0[1],  VF(q0.z), p0b);
        p1a = fmaf(aw1[0],  VF(q0.x), p1a); p1b = fmaf(aw1[1],  VF(q0.z), p1b);
        p0a = fmaf(aw0[2],  VF(q1.x), p0a); p0b = fmaf(aw0[3],  VF(q1.z), p0b);
        p1a = fmaf(aw1[2],  VF(q1.x), p1a); p1b = fmaf(aw1[3],  VF(q1.z), p1b);
        p0a = fmaf(aw0[4],  VF(q2.x), p0a); p0b = fmaf(aw0[5],  VF(q2.z), p0b);
        p1a = fmaf(aw1[4],  VF(q2.x), p1a); p1b = fmaf(aw1[5],  VF(q2.z), p1b);
        p0a = fmaf(aw0[6],  VF(q3.x), p0a); p0b = fmaf(aw0[7],  VF(q3.z), p0b);
        p1a = fmaf(aw1[6],  VF(q3.x), p1a); p1b = fmaf(aw1[7],  VF(q3.z), p1b);
        p0a = fmaf(aw0[8],  VF(q4.x), p0a); p0b = fmaf(aw0[9],  VF(q4.z), p0b);
        p1a = fmaf(aw1[8],  VF(q4.x), p1a); p1b = fmaf(aw1[9],  VF(q4.z), p1b);
        p0a = fmaf(aw0[10], VF(q5.x), p0a); p0b = fmaf(aw0[11], VF(q5.z), p0b);
        p1a = fmaf(aw1[10], VF(q5.x), p1a); p1b = fmaf(aw1[11], VF(q5.z), p1b);
        p0a = fmaf(aw0[12], VF(q6.x), p0a); p0b = fmaf(aw0[13], VF(q6.z), p0b);
        p1a = fmaf(aw1[12], VF(q6.x), p1a); p1b = fmaf(aw1[13], VF(q6.z), p1b);
        p0a = fmaf(aw0[14], VF(q7.x), p0a); p0b = fmaf(aw0[15], VF(q7.z), p0b);
        p1a = fmaf(aw1[14], VF(q7.x), p1a); p1b = fmaf(aw1[15], VF(q7.z), p1b);
        float p0 = p0a + p0b;
        float p1 = p1a + p1b;

        // Wave-wide sums via DPP (validated round 6); full sums in lane 63.
        DPP_ADD(p0, 0x111, 0xf); DPP_ADD(p1, 0x111, 0xf);  // row_shr:1
        DPP_ADD(p0, 0x112, 0xf); DPP_ADD(p1, 0x112, 0xf);  // row_shr:2
        DPP_ADD(p0, 0x114, 0xf); DPP_ADD(p1, 0x114, 0xf);  // row_shr:4
        DPP_ADD(p0, 0x118, 0xf); DPP_ADD(p1, 0x118, 0xf);  // row_shr:8
        DPP_ADD(p0, 0x142, 0xa); DPP_ADD(p1, 0x142, 0xa);  // row_bcast:15
        DPP_ADD(p0, 0x143, 0xc); DPP_ADD(p1, 0x143, 0xc);  // row_bcast:31

        if (lane == 63) {
            const float h0n = fast_tanh(p0 + bx.x);
            const float h1n = fast_tanh(p1 + bx.y);
            union { float f; unsigned u; } u0, u1; u0.f = h0n; u1.f = h1n;
            uint32x4 pkt;
            pkt.x = u0.u; pkt.y = (unsigned)(t + 1);
            pkt.z = u1.u; pkt.w = (unsigned)(t + 1);
            unsigned long long* dp = slots + ((size_t)(t & 3) << 10) + r0;
            // Packet store FIRST (inter-block critical path), out second.
            asm volatile(
                "global_store_dwordx4 %0, %1, off sc0 sc1"
                :: "v"(dp), "v"(pkt) : "memory");
            *(float2*)&out[(size_t)t * HD + r0] = make_float2(h0n, h1n);
        }
        // No barrier anywhere: tags + 4-deep ring + all-to-all dataflow
        // (skew <= 1) are the synchronization.
    }
}

// ---------------------------------------------------------------------------
extern "C" void kernel_launch(void* const* d_in, const int* in_sizes, int n_in,
                              void* d_out, int out_size, void* d_ws, size_t ws_size,
                              hipStream_t stream)
{
    const float* x     = (const float*)d_in[0];  // [16384, 512]
    const float* h0    = (const float*)d_in[1];  // [1024]
    const float* A_raw = (const float*)d_in[2];  // [1024, 1024]
    const float* B     = (const float*)d_in[3];  // [1024, 512]
    const float* c     = (const float*)d_in[4];  // [1024]
    float* out = (float*)d_out;                  // [16384, 1024]
    unsigned long long* slots = (unsigned long long*)d_ws;  // 4 x 1024 x 8B

    dim3 gemm_grid(T_STEPS / 64, HD / 64);       // 256 x 16
    gemm_bx_kernel<<<gemm_grid, 256, 0, stream>>>(x, B, c, out);
    init_slots_kernel<<<1, HD, 0, stream>>>(slots, h0);
    rnn_scan_kernel<<<64, 512, 0, stream>>>(A_raw, out, slots);
}